// Round 3
// baseline (273.377 us; speedup 1.0000x reference)
//
#include <hip/hip_runtime.h>
#include <hip/hip_bf16.h>
#include <stdint.h>

#define D_MODEL 1024
#define BM 128
#define BN 128
#define BK 64   // bf16 elems; 128 B rows -> 8-slot XOR swizzle is conflict-free

typedef __attribute__((ext_vector_type(4))) float  f32x4;
typedef __attribute__((ext_vector_type(8))) __bf16 bf16x8;
typedef __attribute__((ext_vector_type(8))) unsigned short u16x8;
typedef __attribute__((ext_vector_type(4))) unsigned short u16x4;

// ---------- helpers ----------

// monotonic float->uint map so unsigned atomicMax == float max
__device__ __forceinline__ unsigned order_map(float x) {
    unsigned u = __float_as_uint(x);
    return (u & 0x80000000u) ? ~u : (u | 0x80000000u);
}
__device__ __forceinline__ float order_unmap(unsigned m) {
    unsigned b = (m & 0x80000000u) ? (m & 0x7fffffffu) : ~m;
    return __uint_as_float(b);
}
// f32 -> bf16 bits, round-to-nearest-even
__device__ __forceinline__ unsigned short f2bf(float f) {
    unsigned u = __float_as_uint(f);
    u += 0x7fffu + ((u >> 16) & 1u);
    return (unsigned short)(u >> 16);
}

// ---------- prelude kernels ----------

__global__ void init_u32(unsigned* __restrict__ p, int n) {
    int i = blockIdx.x * blockDim.x + threadIdx.x;
    if (i < n) p[i] = 0u;
}

// plain column max (fallback for x; always used for weight)
__global__ void colmax_kernel(const float* __restrict__ src, int rows_per_slab,
                              int cols, unsigned* __restrict__ out_u) {
    int k = blockIdx.x * blockDim.x + threadIdx.x;
    const float* p = src + (size_t)blockIdx.y * rows_per_slab * cols + k;
    float m = -__builtin_inff();
#pragma unroll 4
    for (int r = 0; r < rows_per_slab; ++r)
        m = fmaxf(m, p[(size_t)r * cols]);
    atomicMax(&out_u[k], order_map(m));
}

// fused: column max of x AND f32->bf16 convert into Xb.
// 256 thr x 4 cols (full row width), ROWS_PER_BLK rows per block.
// grid = N / ROWS_PER_BLK = 2048 -> 8 blocks/CU, full latency hiding.
#define CC_ROWS 16
__global__ __launch_bounds__(256)
void colmax_convert(const float* __restrict__ x,
                    unsigned* __restrict__ ma_u,
                    unsigned short* __restrict__ xb) {
    int c4 = threadIdx.x * 4;
    size_t base = (size_t)blockIdx.x * CC_ROWS * D_MODEL + c4;
    f32x4 m4 = {-__builtin_inff(), -__builtin_inff(), -__builtin_inff(), -__builtin_inff()};
#pragma unroll 8
    for (int r = 0; r < CC_ROWS; ++r) {
        f32x4 v = *reinterpret_cast<const f32x4*>(&x[base + (size_t)r * D_MODEL]);
        u16x4 o;
#pragma unroll
        for (int e = 0; e < 4; ++e) { m4[e] = fmaxf(m4[e], v[e]); o[e] = f2bf(v[e]); }
        *reinterpret_cast<u16x4*>(&xb[base + (size_t)r * D_MODEL]) = o;
    }
#pragma unroll
    for (int e = 0; e < 4; ++e) atomicMax(&ma_u[c4 + e], order_map(m4[e]));
}

__global__ void scale_kernel(const unsigned* __restrict__ ma_u,
                             const unsigned* __restrict__ mw_u,
                             float* __restrict__ s) {
    int k = blockIdx.x * blockDim.x + threadIdx.x;
    if (k < D_MODEL) {
        float ma = order_unmap(ma_u[k]);
        float mw = order_unmap(mw_u[k]);
        s[k] = sqrtf(ma) / sqrtf(mw);   // ALPHA = 0.5
    }
}

// W'[j,k] = bf16( s[j] * W[j,k] / s[k] )
__global__ void build_w_kernel(const float* __restrict__ W, const float* __restrict__ s,
                               unsigned short* __restrict__ Wp) {
    int j  = blockIdx.x;
    int k4 = threadIdx.x * 4;
    float sj = s[j];
    f32x4 w  = *reinterpret_cast<const f32x4*>(&W[(size_t)j * D_MODEL + k4]);
    f32x4 sk = *reinterpret_cast<const f32x4*>(&s[k4]);
    u16x4 o;
#pragma unroll
    for (int i = 0; i < 4; ++i) o[i] = f2bf(sj * w[i] / sk[i]);
    *reinterpret_cast<u16x4*>(&Wp[(size_t)j * D_MODEL + k4]) = o;
}

// ---------- GEMM ----------
// out[N,D] = X @ Wp^T + bias. 128x128 tile, BK=64, 4 waves (2x2), 16x16x32 MFMA.
// LDS XOR-swizzle: phys_off(row, o) = o ^ ((row&7)<<4)  [bytes, 16B slots].
// B (and A when PRECONV) staged via global_load_lds: linear LDS dest,
// pre-swizzled GLOBAL source (rule: both-sides-or-neither), swizzled read.
template <bool PRECONV>
__global__ __launch_bounds__(256)
void gemm_kernel(const float* __restrict__ X, const unsigned short* __restrict__ Xb,
                 const unsigned short* __restrict__ Wp, const float* __restrict__ bias,
                 float* __restrict__ out, int N) {
    __shared__ __align__(16) unsigned short As[BM][BK];   // 16 KB
    __shared__ __align__(16) unsigned short Bs[BN][BK];   // 16 KB

    // XCD-aware swizzle (grid = 2048, %8==0 -> bijective)
    int flat = blockIdx.x;
    int swz  = ((gridDim.x & 7) == 0)
             ? (flat & 7) * (gridDim.x >> 3) + (flat >> 3)
             : flat;
    const int nColBlk = D_MODEL / BN;   // 8
    int row0 = (swz / nColBlk) * BM;
    int col0 = (swz % nColBlk) * BN;

    int tid  = threadIdx.x;
    int wave = tid >> 6;
    int lane = tid & 63;
    int wr   = wave >> 1;
    int wc   = wave & 1;
    int l16  = lane & 15;

    // static per-lane source pre-swizzle for global_load_lds staging:
    // lane l fills linear LDS slot (row r0+(l>>3), slot l&7); content there must be
    // logical slot (l&7)^(l>>3)  [16B slots of 8 bf16]
    int srow = lane >> 3;                       // 0..7 within 8-row group
    int skoff = ((lane & 7) ^ srow) << 3;       // bf16 elems within 64-elem row

    f32x4 acc[4][4];
#pragma unroll
    for (int m = 0; m < 4; ++m)
#pragma unroll
        for (int n = 0; n < 4; ++n)
            acc[m][n] = (f32x4){0.f, 0.f, 0.f, 0.f};

    for (int k0 = 0; k0 < D_MODEL; k0 += BK) {
        __syncthreads();

        // ---- stage A ----
        if (PRECONV) {
#pragma unroll
            for (int i = 0; i < 4; ++i) {
                int r0 = (wave * 4 + i) * 8;
                const unsigned short* g = Xb + (size_t)(row0 + r0 + srow) * D_MODEL + k0 + skoff;
                __builtin_amdgcn_global_load_lds(
                    (const __attribute__((address_space(1))) void*)g,
                    (__attribute__((address_space(3))) void*)&As[r0][0], 16, 0, 0);
            }
        } else {
            // reg-stage f32 -> bf16, swizzled ds_write
#pragma unroll
            for (int i = 0; i < 4; ++i) {
                int c   = i * 256 + tid;      // 0..1023
                int r   = c >> 3;             // row 0..127
                int seg = c & 7;              // 8-elem segment
                const float* gp = X + (size_t)(row0 + r) * D_MODEL + k0 + seg * 8;
                f32x4 x0 = *reinterpret_cast<const f32x4*>(gp);
                f32x4 x1 = *reinterpret_cast<const f32x4*>(gp + 4);
                u16x8 v;
#pragma unroll
                for (int e = 0; e < 4; ++e) { v[e] = f2bf(x0[e]); v[e + 4] = f2bf(x1[e]); }
                int off = (seg * 16) ^ ((r & 7) << 4);
                *reinterpret_cast<u16x8*>((char*)&As[0][0] + r * 128 + off) = v;
            }
        }

        // ---- stage B ----
#pragma unroll
        for (int i = 0; i < 4; ++i) {
            int r0 = (wave * 4 + i) * 8;
            const unsigned short* g = Wp + (size_t)(col0 + r0 + srow) * D_MODEL + k0 + skoff;
            __builtin_amdgcn_global_load_lds(
                (const __attribute__((address_space(1))) void*)g,
                (__attribute__((address_space(3))) void*)&Bs[r0][0], 16, 0, 0);
        }

        __syncthreads();

        // ---- compute: 2 k-substeps x (8 ds_read_b128 + 16 MFMA) ----
#pragma unroll
        for (int kk = 0; kk < 2; ++kk) {
            bf16x8 af[4], bf_[4];
#pragma unroll
            for (int m = 0; m < 4; ++m) {
                int row = wr * 64 + m * 16 + l16;
                int o   = ((lane >> 4) * 16 + kk * 64) ^ ((row & 7) << 4);
                af[m] = *reinterpret_cast<const bf16x8*>((const char*)&As[0][0] + row * 128 + o);
            }
#pragma unroll
            for (int n = 0; n < 4; ++n) {
                int row = wc * 64 + n * 16 + l16;
                int o   = ((lane >> 4) * 16 + kk * 64) ^ ((row & 7) << 4);
                bf_[n] = *reinterpret_cast<const bf16x8*>((const char*)&Bs[0][0] + row * 128 + o);
            }
#pragma unroll
            for (int m = 0; m < 4; ++m)
#pragma unroll
                for (int n = 0; n < 4; ++n)
                    acc[m][n] = __builtin_amdgcn_mfma_f32_16x16x32_bf16(
                        af[m], bf_[n], acc[m][n], 0, 0, 0);
        }
    }

    // ---- epilogue: C/D col = lane&15, row = (lane>>4)*4 + q ----
    int crow = row0 + wr * 64;
    int ccol = col0 + wc * 64;
#pragma unroll
    for (int n = 0; n < 4; ++n) {
        int col = ccol + n * 16 + l16;
        float b = bias[col];
#pragma unroll
        for (int m = 0; m < 4; ++m) {
            int r = crow + m * 16 + (lane >> 4) * 4;
#pragma unroll
            for (int q = 0; q < 4; ++q)
                out[(size_t)(r + q) * D_MODEL + col] = acc[m][n][q] + b;
        }
    }
}

// ---------- launch ----------

extern "C" void kernel_launch(void* const* d_in, const int* in_sizes, int n_in,
                              void* d_out, int out_size, void* d_ws, size_t ws_size,
                              hipStream_t stream) {
    const float* x    = (const float*)d_in[0];
    const float* w    = (const float*)d_in[1];
    const float* bias = (const float*)d_in[2];
    float* out        = (float*)d_out;
    const int N       = in_sizes[0] / D_MODEL;   // 32768

    // ws layout: [0,4K) ma_u | [4K,8K) mw_u | [8K,12K) s | [16K,16K+2M) Wp | then Xb
    char* ws               = (char*)d_ws;
    unsigned*       ma_u   = (unsigned*)(ws);
    unsigned*       mw_u   = (unsigned*)(ws + 4096);
    float*          s      = (float*)(ws + 8192);
    unsigned short* Wp     = (unsigned short*)(ws + 16384);
    unsigned short* Xb     = (unsigned short*)(ws + 16384 + (size_t)D_MODEL * D_MODEL * 2);

    size_t need = 16384 + (size_t)D_MODEL * D_MODEL * 2 + (size_t)N * D_MODEL * 2;
    bool preconv = ws_size >= need;

    init_u32<<<8, 256, 0, stream>>>((unsigned*)ws, 2048);

    if (preconv) {
        // N/CC_ROWS = 2048 blocks (8/CU): colmax of x + bf16 convert in one pass
        colmax_convert<<<N / CC_ROWS, 256, 0, stream>>>(x, ma_u, Xb);
    } else {
        colmax_kernel<<<dim3(D_MODEL / 256, 64), 256, 0, stream>>>(x, N / 64, D_MODEL, ma_u);
    }
    colmax_kernel<<<dim3(D_MODEL / 256, 16), 256, 0, stream>>>(w, D_MODEL / 16, D_MODEL, mw_u);
    scale_kernel<<<D_MODEL / 256, 256, 0, stream>>>(ma_u, mw_u, s);
    build_w_kernel<<<D_MODEL, 256, 0, stream>>>(w, s, Wp);

    int nblk = (N / BM) * (D_MODEL / BN);   // 2048
    if (preconv)
        gemm_kernel<true ><<<nblk, 256, 0, stream>>>(x, Xb, Wp, bias, out, N);
    else
        gemm_kernel<false><<<nblk, 256, 0, stream>>>(x, Xb, Wp, bias, out, N);
}

// Round 4
// 161.939 us; speedup vs baseline: 1.6881x; 1.6881x over previous
//
#include <hip/hip_runtime.h>
#include <hip/hip_bf16.h>
#include <stdint.h>

#define D_MODEL 1024
#define BM 128
#define BN 128
#define BK 64   // bf16 elems; 128 B rows -> 8-slot XOR swizzle is conflict-free

typedef __attribute__((ext_vector_type(4))) float  f32x4;
typedef __attribute__((ext_vector_type(8))) __bf16 bf16x8;
typedef __attribute__((ext_vector_type(8))) unsigned short u16x8;
typedef __attribute__((ext_vector_type(4))) unsigned short u16x4;

// ---------- helpers ----------

// monotonic float->uint map so unsigned atomicMax == float max
__device__ __forceinline__ unsigned order_map(float x) {
    unsigned u = __float_as_uint(x);
    return (u & 0x80000000u) ? ~u : (u | 0x80000000u);
}
__device__ __forceinline__ float order_unmap(unsigned m) {
    unsigned b = (m & 0x80000000u) ? (m & 0x7fffffffu) : ~m;
    return __uint_as_float(b);
}
// f32 -> bf16 bits, round-to-nearest-even
__device__ __forceinline__ unsigned short f2bf(float f) {
    unsigned u = __float_as_uint(f);
    u += 0x7fffu + ((u >> 16) & 1u);
    return (unsigned short)(u >> 16);
}

// ---------- prelude kernels ----------

__global__ void init_u32(unsigned* __restrict__ p, int n) {
    int i = blockIdx.x * blockDim.x + threadIdx.x;
    if (i < n) p[i] = 0u;
}

// plain column max (fallback for x; always used for weight). few blocks -> cheap atomics.
__global__ void colmax_kernel(const float* __restrict__ src, int rows_per_slab,
                              int cols, unsigned* __restrict__ out_u) {
    int k = blockIdx.x * blockDim.x + threadIdx.x;
    const float* p = src + (size_t)blockIdx.y * rows_per_slab * cols + k;
    float m = -__builtin_inff();
#pragma unroll 4
    for (int r = 0; r < rows_per_slab; ++r)
        m = fmaxf(m, p[(size_t)r * cols]);
    atomicMax(&out_u[k], order_map(m));
}

// Stage A: column max of x (per-block partials, NO atomics) + f32->bf16 convert.
// 2048 blocks (8/CU), 256 thr x 4 cols, 16 rows/block.
#define CC_ROWS 16
__global__ __launch_bounds__(256)
void colmax_convert(const float* __restrict__ x,
                    float* __restrict__ partial,
                    unsigned short* __restrict__ xb) {
    int c4 = threadIdx.x * 4;
    size_t base = (size_t)blockIdx.x * CC_ROWS * D_MODEL + c4;
    f32x4 m4 = {-__builtin_inff(), -__builtin_inff(), -__builtin_inff(), -__builtin_inff()};
#pragma unroll 8
    for (int r = 0; r < CC_ROWS; ++r) {
        f32x4 v = *reinterpret_cast<const f32x4*>(&x[base + (size_t)r * D_MODEL]);
        u16x4 o;
#pragma unroll
        for (int e = 0; e < 4; ++e) { m4[e] = fmaxf(m4[e], v[e]); o[e] = f2bf(v[e]); }
        *reinterpret_cast<u16x4*>(&xb[base + (size_t)r * D_MODEL]) = o;
    }
    // plain coalesced store of this block's 4 partials per thread
    *reinterpret_cast<f32x4*>(&partial[(size_t)blockIdx.x * D_MODEL + c4]) = m4;
}

// Stage B: reduce partial[2048][1024] over block axis. grid (4, 32):
// 32 slabs x 64 partial-rows; one atomicMax per thread (32K total).
__global__ void reduce_partial(const float* __restrict__ partial,
                               unsigned* __restrict__ ma_u) {
    int col  = blockIdx.x * 256 + threadIdx.x;
    int b0   = blockIdx.y * 64;
    float m = -__builtin_inff();
#pragma unroll 8
    for (int i = 0; i < 64; ++i)
        m = fmaxf(m, partial[(size_t)(b0 + i) * D_MODEL + col]);
    atomicMax(&ma_u[col], order_map(m));
}

__global__ void scale_kernel(const unsigned* __restrict__ ma_u,
                             const unsigned* __restrict__ mw_u,
                             float* __restrict__ s) {
    int k = blockIdx.x * blockDim.x + threadIdx.x;
    if (k < D_MODEL) {
        float ma = order_unmap(ma_u[k]);
        float mw = order_unmap(mw_u[k]);
        s[k] = sqrtf(ma) / sqrtf(mw);   // ALPHA = 0.5
    }
}

// W'[j,k] = bf16( s[j] * W[j,k] / s[k] )
__global__ void build_w_kernel(const float* __restrict__ W, const float* __restrict__ s,
                               unsigned short* __restrict__ Wp) {
    int j  = blockIdx.x;
    int k4 = threadIdx.x * 4;
    float sj = s[j];
    f32x4 w  = *reinterpret_cast<const f32x4*>(&W[(size_t)j * D_MODEL + k4]);
    f32x4 sk = *reinterpret_cast<const f32x4*>(&s[k4]);
    u16x4 o;
#pragma unroll
    for (int i = 0; i < 4; ++i) o[i] = f2bf(sj * w[i] / sk[i]);
    *reinterpret_cast<u16x4*>(&Wp[(size_t)j * D_MODEL + k4]) = o;
}

// ---------- GEMM ----------
// out[N,D] = X @ Wp^T + bias. 128x128 tile, BK=64, 4 waves (2x2), 16x16x32 MFMA.
// LDS XOR-swizzle: phys_off(row, o) = o ^ ((row&7)<<4)  [bytes, 16B slots].
// B (and A when PRECONV) staged via global_load_lds: linear LDS dest,
// pre-swizzled GLOBAL source (rule: both-sides-or-neither), swizzled read.
template <bool PRECONV>
__global__ __launch_bounds__(256)
void gemm_kernel(const float* __restrict__ X, const unsigned short* __restrict__ Xb,
                 const unsigned short* __restrict__ Wp, const float* __restrict__ bias,
                 float* __restrict__ out, int N) {
    __shared__ __align__(16) unsigned short As[BM][BK];   // 16 KB
    __shared__ __align__(16) unsigned short Bs[BN][BK];   // 16 KB

    // XCD-aware swizzle (grid = 2048, %8==0 -> bijective)
    int flat = blockIdx.x;
    int swz  = ((gridDim.x & 7) == 0)
             ? (flat & 7) * (gridDim.x >> 3) + (flat >> 3)
             : flat;
    const int nColBlk = D_MODEL / BN;   // 8
    int row0 = (swz / nColBlk) * BM;
    int col0 = (swz % nColBlk) * BN;

    int tid  = threadIdx.x;
    int wave = tid >> 6;
    int lane = tid & 63;
    int wr   = wave >> 1;
    int wc   = wave & 1;
    int l16  = lane & 15;

    // static per-lane source pre-swizzle for global_load_lds staging:
    // lane l fills linear LDS slot (row r0+(l>>3), slot l&7); content there must be
    // logical slot (l&7)^(l>>3)  [16B slots of 8 bf16]
    int srow = lane >> 3;                       // 0..7 within 8-row group
    int skoff = ((lane & 7) ^ srow) << 3;       // bf16 elems within 64-elem row

    f32x4 acc[4][4];
#pragma unroll
    for (int m = 0; m < 4; ++m)
#pragma unroll
        for (int n = 0; n < 4; ++n)
            acc[m][n] = (f32x4){0.f, 0.f, 0.f, 0.f};

    for (int k0 = 0; k0 < D_MODEL; k0 += BK) {
        __syncthreads();

        // ---- stage A ----
        if (PRECONV) {
#pragma unroll
            for (int i = 0; i < 4; ++i) {
                int r0 = (wave * 4 + i) * 8;
                const unsigned short* g = Xb + (size_t)(row0 + r0 + srow) * D_MODEL + k0 + skoff;
                __builtin_amdgcn_global_load_lds(
                    (const __attribute__((address_space(1))) void*)g,
                    (__attribute__((address_space(3))) void*)&As[r0][0], 16, 0, 0);
            }
        } else {
            // reg-stage f32 -> bf16, swizzled ds_write
#pragma unroll
            for (int i = 0; i < 4; ++i) {
                int c   = i * 256 + tid;      // 0..1023
                int r   = c >> 3;             // row 0..127
                int seg = c & 7;              // 8-elem segment
                const float* gp = X + (size_t)(row0 + r) * D_MODEL + k0 + seg * 8;
                f32x4 x0 = *reinterpret_cast<const f32x4*>(gp);
                f32x4 x1 = *reinterpret_cast<const f32x4*>(gp + 4);
                u16x8 v;
#pragma unroll
                for (int e = 0; e < 4; ++e) { v[e] = f2bf(x0[e]); v[e + 4] = f2bf(x1[e]); }
                int off = (seg * 16) ^ ((r & 7) << 4);
                *reinterpret_cast<u16x8*>((char*)&As[0][0] + r * 128 + off) = v;
            }
        }

        // ---- stage B ----
#pragma unroll
        for (int i = 0; i < 4; ++i) {
            int r0 = (wave * 4 + i) * 8;
            const unsigned short* g = Wp + (size_t)(col0 + r0 + srow) * D_MODEL + k0 + skoff;
            __builtin_amdgcn_global_load_lds(
                (const __attribute__((address_space(1))) void*)g,
                (__attribute__((address_space(3))) void*)&Bs[r0][0], 16, 0, 0);
        }

        __syncthreads();

        // ---- compute: 2 k-substeps x (8 ds_read_b128 + 16 MFMA) ----
#pragma unroll
        for (int kk = 0; kk < 2; ++kk) {
            bf16x8 af[4], bf_[4];
#pragma unroll
            for (int m = 0; m < 4; ++m) {
                int row = wr * 64 + m * 16 + l16;
                int o   = ((lane >> 4) * 16 + kk * 64) ^ ((row & 7) << 4);
                af[m] = *reinterpret_cast<const bf16x8*>((const char*)&As[0][0] + row * 128 + o);
            }
#pragma unroll
            for (int n = 0; n < 4; ++n) {
                int row = wc * 64 + n * 16 + l16;
                int o   = ((lane >> 4) * 16 + kk * 64) ^ ((row & 7) << 4);
                bf_[n] = *reinterpret_cast<const bf16x8*>((const char*)&Bs[0][0] + row * 128 + o);
            }
#pragma unroll
            for (int m = 0; m < 4; ++m)
#pragma unroll
                for (int n = 0; n < 4; ++n)
                    acc[m][n] = __builtin_amdgcn_mfma_f32_16x16x32_bf16(
                        af[m], bf_[n], acc[m][n], 0, 0, 0);
        }
    }

    // ---- epilogue: C/D col = lane&15, row = (lane>>4)*4 + q ----
    int crow = row0 + wr * 64;
    int ccol = col0 + wc * 64;
#pragma unroll
    for (int n = 0; n < 4; ++n) {
        int col = ccol + n * 16 + l16;
        float b = bias[col];
#pragma unroll
        for (int m = 0; m < 4; ++m) {
            int r = crow + m * 16 + (lane >> 4) * 4;
#pragma unroll
            for (int q = 0; q < 4; ++q)
                out[(size_t)(r + q) * D_MODEL + col] = acc[m][n][q] + b;
        }
    }
}

// ---------- launch ----------

extern "C" void kernel_launch(void* const* d_in, const int* in_sizes, int n_in,
                              void* d_out, int out_size, void* d_ws, size_t ws_size,
                              hipStream_t stream) {
    const float* x    = (const float*)d_in[0];
    const float* w    = (const float*)d_in[1];
    const float* bias = (const float*)d_in[2];
    float* out        = (float*)d_out;
    const int N       = in_sizes[0] / D_MODEL;   // 32768

    // ws layout: [0,4K) ma_u | [4K,8K) mw_u | [8K,12K) s | [16K,16K+2M) Wp |
    //            Xb (N*D bf16) | partial (N/CC_ROWS * D f32)
    char* ws               = (char*)d_ws;
    unsigned*       ma_u   = (unsigned*)(ws);
    unsigned*       mw_u   = (unsigned*)(ws + 4096);
    float*          s      = (float*)(ws + 8192);
    unsigned short* Wp     = (unsigned short*)(ws + 16384);
    unsigned short* Xb     = (unsigned short*)(ws + 16384 + (size_t)D_MODEL * D_MODEL * 2);
    const int nPart        = N / CC_ROWS;   // 2048
    float*          part   = (float*)(ws + 16384 + (size_t)D_MODEL * D_MODEL * 2
                                               + (size_t)N * D_MODEL * 2);

    size_t need = 16384 + (size_t)D_MODEL * D_MODEL * 2 + (size_t)N * D_MODEL * 2
                + (size_t)nPart * D_MODEL * 4;
    bool preconv = ws_size >= need;

    init_u32<<<8, 256, 0, stream>>>((unsigned*)ws, 2048);

    if (preconv) {
        colmax_convert<<<nPart, 256, 0, stream>>>(x, part, Xb);
        reduce_partial<<<dim3(D_MODEL / 256, nPart / 64), 256, 0, stream>>>(part, ma_u);
    } else {
        colmax_kernel<<<dim3(D_MODEL / 256, 64), 256, 0, stream>>>(x, N / 64, D_MODEL, ma_u);
    }
    colmax_kernel<<<dim3(D_MODEL / 256, 16), 256, 0, stream>>>(w, D_MODEL / 16, D_MODEL, mw_u);
    scale_kernel<<<D_MODEL / 256, 256, 0, stream>>>(ma_u, mw_u, s);
    build_w_kernel<<<D_MODEL, 256, 0, stream>>>(w, s, Wp);

    int nblk = (N / BM) * (D_MODEL / BN);   // 2048
    if (preconv)
        gemm_kernel<true ><<<nblk, 256, 0, stream>>>(x, Xb, Wp, bias, out, N);
    else
        gemm_kernel<false><<<nblk, 256, 0, stream>>>(x, Xb, Wp, bias, out, N);
}

// Round 5
// 161.768 us; speedup vs baseline: 1.6899x; 1.0011x over previous
//
#include <hip/hip_runtime.h>
#include <hip/hip_bf16.h>
#include <stdint.h>

#define D_MODEL 1024
#define BM 128
#define BN 128
#define BK 64   // bf16 elems; 128 B rows -> 8-slot XOR swizzle is conflict-free

typedef __attribute__((ext_vector_type(4))) float  f32x4;
typedef __attribute__((ext_vector_type(8))) __bf16 bf16x8;
typedef __attribute__((ext_vector_type(8))) unsigned short u16x8;
typedef __attribute__((ext_vector_type(4))) unsigned short u16x4;

// ---------- helpers ----------

__device__ __forceinline__ unsigned order_map(float x) {
    unsigned u = __float_as_uint(x);
    return (u & 0x80000000u) ? ~u : (u | 0x80000000u);
}
__device__ __forceinline__ float order_unmap(unsigned m) {
    unsigned b = (m & 0x80000000u) ? (m & 0x7fffffffu) : ~m;
    return __uint_as_float(b);
}
__device__ __forceinline__ unsigned short f2bf(float f) {
    unsigned u = __float_as_uint(f);
    u += 0x7fffu + ((u >> 16) & 1u);
    return (unsigned short)(u >> 16);
}

// ---------- prelude kernels ----------

__global__ void init_u32(unsigned* __restrict__ p, int n) {
    int i = blockIdx.x * blockDim.x + threadIdx.x;
    if (i < n) p[i] = 0u;
}

__global__ void colmax_kernel(const float* __restrict__ src, int rows_per_slab,
                              int cols, unsigned* __restrict__ out_u) {
    int k = blockIdx.x * blockDim.x + threadIdx.x;
    const float* p = src + (size_t)blockIdx.y * rows_per_slab * cols + k;
    float m = -__builtin_inff();
#pragma unroll 4
    for (int r = 0; r < rows_per_slab; ++r)
        m = fmaxf(m, p[(size_t)r * cols]);
    atomicMax(&out_u[k], order_map(m));
}

// Stage A: column max of x (per-block partials, NO atomics) + f32->bf16 convert.
#define CC_ROWS 16
__global__ __launch_bounds__(256)
void colmax_convert(const float* __restrict__ x,
                    float* __restrict__ partial,
                    unsigned short* __restrict__ xb) {
    int c4 = threadIdx.x * 4;
    size_t base = (size_t)blockIdx.x * CC_ROWS * D_MODEL + c4;
    f32x4 m4 = {-__builtin_inff(), -__builtin_inff(), -__builtin_inff(), -__builtin_inff()};
#pragma unroll 8
    for (int r = 0; r < CC_ROWS; ++r) {
        f32x4 v = *reinterpret_cast<const f32x4*>(&x[base + (size_t)r * D_MODEL]);
        u16x4 o;
#pragma unroll
        for (int e = 0; e < 4; ++e) { m4[e] = fmaxf(m4[e], v[e]); o[e] = f2bf(v[e]); }
        *reinterpret_cast<u16x4*>(&xb[base + (size_t)r * D_MODEL]) = o;
    }
    *reinterpret_cast<f32x4*>(&partial[(size_t)blockIdx.x * D_MODEL + c4]) = m4;
}

__global__ void reduce_partial(const float* __restrict__ partial,
                               unsigned* __restrict__ ma_u) {
    int col  = blockIdx.x * 256 + threadIdx.x;
    int b0   = blockIdx.y * 64;
    float m = -__builtin_inff();
#pragma unroll 8
    for (int i = 0; i < 64; ++i)
        m = fmaxf(m, partial[(size_t)(b0 + i) * D_MODEL + col]);
    atomicMax(&ma_u[col], order_map(m));
}

__global__ void scale_kernel(const unsigned* __restrict__ ma_u,
                             const unsigned* __restrict__ mw_u,
                             float* __restrict__ s) {
    int k = blockIdx.x * blockDim.x + threadIdx.x;
    if (k < D_MODEL) {
        float ma = order_unmap(ma_u[k]);
        float mw = order_unmap(mw_u[k]);
        s[k] = sqrtf(ma) / sqrtf(mw);   // ALPHA = 0.5
    }
}

__global__ void build_w_kernel(const float* __restrict__ W, const float* __restrict__ s,
                               unsigned short* __restrict__ Wp) {
    int j  = blockIdx.x;
    int k4 = threadIdx.x * 4;
    float sj = s[j];
    f32x4 w  = *reinterpret_cast<const f32x4*>(&W[(size_t)j * D_MODEL + k4]);
    f32x4 sk = *reinterpret_cast<const f32x4*>(&s[k4]);
    u16x4 o;
#pragma unroll
    for (int i = 0; i < 4; ++i) o[i] = f2bf(sj * w[i] / sk[i]);
    *reinterpret_cast<u16x4*>(&Wp[(size_t)j * D_MODEL + k4]) = o;
}

// ---------- GEMM (2-phase double-buffered) ----------
// Per K-step: stage(t+1) issued FIRST (lands during compute), compute(t),
// then vmcnt(0) + one raw s_barrier. No full drain before compute.
__global__ __launch_bounds__(256)
void gemm_db(const unsigned short* __restrict__ Xb,
             const unsigned short* __restrict__ Wp, const float* __restrict__ bias,
             float* __restrict__ out, int N) {
    __shared__ __align__(16) unsigned short As[2][BM][BK];   // 2 x 16 KB
    __shared__ __align__(16) unsigned short Bs[2][BN][BK];   // 2 x 16 KB

    int flat = blockIdx.x;
    int swz  = ((gridDim.x & 7) == 0)
             ? (flat & 7) * (gridDim.x >> 3) + (flat >> 3)
             : flat;
    const int nColBlk = D_MODEL / BN;   // 8
    int row0 = (swz / nColBlk) * BM;
    int col0 = (swz % nColBlk) * BN;

    int tid  = threadIdx.x;
    int wave = tid >> 6;
    int lane = tid & 63;
    int wr   = wave >> 1;
    int wc   = wave & 1;
    int l16  = lane & 15;

    // pre-swizzled global source for linear global_load_lds dest (rule #21)
    int srow  = lane >> 3;                   // 0..7 within 8-row group
    int skoff = ((lane & 7) ^ srow) << 3;    // bf16 elems within 64-elem row

    f32x4 acc[4][4];
#pragma unroll
    for (int m = 0; m < 4; ++m)
#pragma unroll
        for (int n = 0; n < 4; ++n)
            acc[m][n] = (f32x4){0.f, 0.f, 0.f, 0.f};

    const int NT = D_MODEL / BK;   // 16 K-tiles

    // stage one K-tile (A+B, 8 gload_lds/thread) into buffer b
    auto stage = [&](int t, int b) {
        int k0 = t * BK;
#pragma unroll
        for (int i = 0; i < 4; ++i) {
            int r0 = (wave * 4 + i) * 8;
            const unsigned short* gA = Xb + (size_t)(row0 + r0 + srow) * D_MODEL + k0 + skoff;
            __builtin_amdgcn_global_load_lds(
                (const __attribute__((address_space(1))) void*)gA,
                (__attribute__((address_space(3))) void*)&As[b][r0][0], 16, 0, 0);
            const unsigned short* gB = Wp + (size_t)(col0 + r0 + srow) * D_MODEL + k0 + skoff;
            __builtin_amdgcn_global_load_lds(
                (const __attribute__((address_space(1))) void*)gB,
                (__attribute__((address_space(3))) void*)&Bs[b][r0][0], 16, 0, 0);
        }
    };

    stage(0, 0);
    asm volatile("s_waitcnt vmcnt(0)" ::: "memory");
    __builtin_amdgcn_s_barrier();

    for (int t = 0; t < NT; ++t) {
        int cur = t & 1;
        if (t + 1 < NT) stage(t + 1, cur ^ 1);   // issue-early; lands during compute

        // ---- compute tile t from buf[cur]: 2 kk x (8 ds_read_b128 + 16 MFMA) ----
        const char* Ab = (const char*)&As[cur][0][0];
        const char* Bb = (const char*)&Bs[cur][0][0];
#pragma unroll
        for (int kk = 0; kk < 2; ++kk) {
            bf16x8 af[4], bf_[4];
#pragma unroll
            for (int m = 0; m < 4; ++m) {
                int row = wr * 64 + m * 16 + l16;
                int o   = ((lane >> 4) * 16 + kk * 64) ^ ((row & 7) << 4);
                af[m] = *reinterpret_cast<const bf16x8*>(Ab + row * 128 + o);
            }
#pragma unroll
            for (int n = 0; n < 4; ++n) {
                int row = wc * 64 + n * 16 + l16;
                int o   = ((lane >> 4) * 16 + kk * 64) ^ ((row & 7) << 4);
                bf_[n] = *reinterpret_cast<const bf16x8*>(Bb + row * 128 + o);
            }
#pragma unroll
            for (int m = 0; m < 4; ++m)
#pragma unroll
                for (int n = 0; n < 4; ++n)
                    acc[m][n] = __builtin_amdgcn_mfma_f32_16x16x32_bf16(
                        af[m], bf_[n], acc[m][n], 0, 0, 0);
        }

        if (t + 1 < NT) {
            // this step's prefetch had the whole compute to land
            asm volatile("s_waitcnt vmcnt(0)" ::: "memory");
            __builtin_amdgcn_s_barrier();
        }
    }

    // ---- epilogue: C/D col = lane&15, row = (lane>>4)*4 + q ----
    int crow = row0 + wr * 64;
    int ccol = col0 + wc * 64;
#pragma unroll
    for (int n = 0; n < 4; ++n) {
        int col = ccol + n * 16 + l16;
        float b = bias[col];
#pragma unroll
        for (int m = 0; m < 4; ++m) {
            int r = crow + m * 16 + (lane >> 4) * 4;
#pragma unroll
            for (int q = 0; q < 4; ++q)
                out[(size_t)(r + q) * D_MODEL + col] = acc[m][n][q] + b;
        }
    }
}

// fallback (ws too small for Xb): R1-style reg-staged f32->bf16, single buffer
__global__ __launch_bounds__(256)
void gemm_fallback(const float* __restrict__ X, const unsigned short* __restrict__ Wp,
                   const float* __restrict__ bias, float* __restrict__ out, int N) {
    __shared__ __align__(16) unsigned short As[BM][BK];
    __shared__ __align__(16) unsigned short Bs[BN][BK];

    int flat = blockIdx.x;
    int swz  = ((gridDim.x & 7) == 0)
             ? (flat & 7) * (gridDim.x >> 3) + (flat >> 3) : flat;
    const int nColBlk = D_MODEL / BN;
    int row0 = (swz / nColBlk) * BM;
    int col0 = (swz % nColBlk) * BN;

    int tid  = threadIdx.x;
    int wave = tid >> 6;
    int lane = tid & 63;
    int wr   = wave >> 1;
    int wc   = wave & 1;
    int l16  = lane & 15;
    int srow  = lane >> 3;
    int skoff = ((lane & 7) ^ srow) << 3;

    f32x4 acc[4][4];
#pragma unroll
    for (int m = 0; m < 4; ++m)
#pragma unroll
        for (int n = 0; n < 4; ++n)
            acc[m][n] = (f32x4){0.f, 0.f, 0.f, 0.f};

    for (int k0 = 0; k0 < D_MODEL; k0 += BK) {
        __syncthreads();
#pragma unroll
        for (int i = 0; i < 4; ++i) {
            int c   = i * 256 + tid;
            int r   = c >> 3;
            int seg = c & 7;
            const float* gp = X + (size_t)(row0 + r) * D_MODEL + k0 + seg * 8;
            f32x4 x0 = *reinterpret_cast<const f32x4*>(gp);
            f32x4 x1 = *reinterpret_cast<const f32x4*>(gp + 4);
            u16x8 v;
#pragma unroll
            for (int e = 0; e < 4; ++e) { v[e] = f2bf(x0[e]); v[e + 4] = f2bf(x1[e]); }
            int off = (seg * 16) ^ ((r & 7) << 4);
            *reinterpret_cast<u16x8*>((char*)&As[0][0] + r * 128 + off) = v;
        }
#pragma unroll
        for (int i = 0; i < 4; ++i) {
            int r0 = (wave * 4 + i) * 8;
            const unsigned short* g = Wp + (size_t)(col0 + r0 + srow) * D_MODEL + k0 + skoff;
            __builtin_amdgcn_global_load_lds(
                (const __attribute__((address_space(1))) void*)g,
                (__attribute__((address_space(3))) void*)&Bs[r0][0], 16, 0, 0);
        }
        __syncthreads();
#pragma unroll
        for (int kk = 0; kk < 2; ++kk) {
            bf16x8 af[4], bf_[4];
#pragma unroll
            for (int m = 0; m < 4; ++m) {
                int row = wr * 64 + m * 16 + l16;
                int o   = ((lane >> 4) * 16 + kk * 64) ^ ((row & 7) << 4);
                af[m] = *reinterpret_cast<const bf16x8*>((const char*)&As[0][0] + row * 128 + o);
            }
#pragma unroll
            for (int n = 0; n < 4; ++n) {
                int row = wc * 64 + n * 16 + l16;
                int o   = ((lane >> 4) * 16 + kk * 64) ^ ((row & 7) << 4);
                bf_[n] = *reinterpret_cast<const bf16x8*>((const char*)&Bs[0][0] + row * 128 + o);
            }
#pragma unroll
            for (int m = 0; m < 4; ++m)
#pragma unroll
                for (int n = 0; n < 4; ++n)
                    acc[m][n] = __builtin_amdgcn_mfma_f32_16x16x32_bf16(
                        af[m], bf_[n], acc[m][n], 0, 0, 0);
        }
    }

    int crow = row0 + wr * 64;
    int ccol = col0 + wc * 64;
#pragma unroll
    for (int n = 0; n < 4; ++n) {
        int col = ccol + n * 16 + l16;
        float b = bias[col];
#pragma unroll
        for (int m = 0; m < 4; ++m) {
            int r = crow + m * 16 + (lane >> 4) * 4;
#pragma unroll
            for (int q = 0; q < 4; ++q)
                out[(size_t)(r + q) * D_MODEL + col] = acc[m][n][q] + b;
        }
    }
}

// ---------- launch ----------

extern "C" void kernel_launch(void* const* d_in, const int* in_sizes, int n_in,
                              void* d_out, int out_size, void* d_ws, size_t ws_size,
                              hipStream_t stream) {
    const float* x    = (const float*)d_in[0];
    const float* w    = (const float*)d_in[1];
    const float* bias = (const float*)d_in[2];
    float* out        = (float*)d_out;
    const int N       = in_sizes[0] / D_MODEL;   // 32768

    char* ws               = (char*)d_ws;
    unsigned*       ma_u   = (unsigned*)(ws);
    unsigned*       mw_u   = (unsigned*)(ws + 4096);
    float*          s      = (float*)(ws + 8192);
    unsigned short* Wp     = (unsigned short*)(ws + 16384);
    unsigned short* Xb     = (unsigned short*)(ws + 16384 + (size_t)D_MODEL * D_MODEL * 2);
    const int nPart        = N / CC_ROWS;   // 2048
    float*          part   = (float*)(ws + 16384 + (size_t)D_MODEL * D_MODEL * 2
                                               + (size_t)N * D_MODEL * 2);

    size_t need = 16384 + (size_t)D_MODEL * D_MODEL * 2 + (size_t)N * D_MODEL * 2
                + (size_t)nPart * D_MODEL * 4;
    bool preconv = ws_size >= need;

    init_u32<<<8, 256, 0, stream>>>((unsigned*)ws, 2048);

    if (preconv) {
        colmax_convert<<<nPart, 256, 0, stream>>>(x, part, Xb);
        reduce_partial<<<dim3(D_MODEL / 256, nPart / 64), 256, 0, stream>>>(part, ma_u);
    } else {
        colmax_kernel<<<dim3(D_MODEL / 256, 64), 256, 0, stream>>>(x, N / 64, D_MODEL, ma_u);
    }
    colmax_kernel<<<dim3(D_MODEL / 256, 16), 256, 0, stream>>>(w, D_MODEL / 16, D_MODEL, mw_u);
    scale_kernel<<<D_MODEL / 256, 256, 0, stream>>>(ma_u, mw_u, s);
    build_w_kernel<<<D_MODEL, 256, 0, stream>>>(w, s, Wp);

    int nblk = (N / BM) * (D_MODEL / BN);   // 2048
    if (preconv)
        gemm_db<<<nblk, 256, 0, stream>>>(Xb, Wp, bias, out, N);
    else
        gemm_fallback<<<nblk, 256, 0, stream>>>(x, Wp, bias, out, N);
}